// Round 7
// baseline (445.919 us; speedup 1.0000x reference)
//
#include <hip/hip_runtime.h>
#include <math.h>

// Round 7: DIAGNOSTIC — best kernel (Round-5 fused nt) launched TWICE,
// serialized on the same stream. The second launch overwrites out with the
// bit-identical result, so correctness is unchanged, and
//   T_kernel_true = dur_us(round7) - dur_us(round5=405.2)
// resolves the fixed-overhead vs kernel-time ambiguity that top-5-only
// rocprof reporting leaves open (Model A: T~80 -> 2x left; Model B: T~45 ->
// roofline).
//
// x: [B=4, H=16, S=4096, D=128] f32 (134 MB) -> out same shape. pos: [S] i32.
// R input unused (rotations reconstructed analytically).

typedef float v4f __attribute__((ext_vector_type(4)));

#define ROPE_S     4096
#define TAB_N4     (ROPE_S*32)      // 131072 unique (s,c4) rotations
#define NBH        64               // B*H
#define SLICES     16               // bh slices per thread
#define NTHREADS   (TAB_N4*(NBH/SLICES))  // 524288
// -log2(theta)/64 = -log2(10000)/64
#define NEG_L2T_64 (-0.20762050593046012f)

__global__ __launch_bounds__(256) void
RotaryPositionalEmbedding_68332929679843_kernel(const v4f* __restrict__ x,
                                                const int* __restrict__ pos,
                                                v4f* __restrict__ out) {
    const int g   = blockIdx.x * 256 + threadIdx.x;  // 0..524287
    const int tab = g & (TAB_N4 - 1);                // s*32 + c4
    const int bh0 = (g >> 17) * SLICES;              // 0 / 16 / 32 / 48
    const int s   = tab >> 5;
    const int c4  = tab & 31;

    const float p = (float)pos[s];
    const int k   = c4 * 2;
    const float invf0 = exp2f((float)k       * NEG_L2T_64); // theta^(-k/64)
    const float invf1 = exp2f((float)(k + 1) * NEG_L2T_64);
    float s0, c0, s1, c1;
    sincosf(p * invf0, &s0, &c0);
    sincosf(p * invf1, &s1, &c1);

    const size_t base = (size_t)bh0 * TAB_N4 + (size_t)tab;

#pragma unroll
    for (int j = 0; j < SLICES; j += 4) {
        v4f v0 = __builtin_nontemporal_load(&x[base + (size_t)(j + 0) * TAB_N4]);
        v4f v1 = __builtin_nontemporal_load(&x[base + (size_t)(j + 1) * TAB_N4]);
        v4f v2 = __builtin_nontemporal_load(&x[base + (size_t)(j + 2) * TAB_N4]);
        v4f v3 = __builtin_nontemporal_load(&x[base + (size_t)(j + 3) * TAB_N4]);

        v4f o0, o1, o2, o3;
        o0.x = c0 * v0.x - s0 * v0.y;  o0.y = s0 * v0.x + c0 * v0.y;
        o0.z = c1 * v0.z - s1 * v0.w;  o0.w = s1 * v0.z + c1 * v0.w;
        o1.x = c0 * v1.x - s0 * v1.y;  o1.y = s0 * v1.x + c0 * v1.y;
        o1.z = c1 * v1.z - s1 * v1.w;  o1.w = s1 * v1.z + c1 * v1.w;
        o2.x = c0 * v2.x - s0 * v2.y;  o2.y = s0 * v2.x + c0 * v2.y;
        o2.z = c1 * v2.z - s1 * v2.w;  o2.w = s1 * v2.z + c1 * v2.w;
        o3.x = c0 * v3.x - s0 * v3.y;  o3.y = s0 * v3.x + c0 * v3.y;
        o3.z = c1 * v3.z - s1 * v3.w;  o3.w = s1 * v3.z + c1 * v3.w;

        __builtin_nontemporal_store(o0, &out[base + (size_t)(j + 0) * TAB_N4]);
        __builtin_nontemporal_store(o1, &out[base + (size_t)(j + 1) * TAB_N4]);
        __builtin_nontemporal_store(o2, &out[base + (size_t)(j + 2) * TAB_N4]);
        __builtin_nontemporal_store(o3, &out[base + (size_t)(j + 3) * TAB_N4]);
    }
}

extern "C" void kernel_launch(void* const* d_in, const int* in_sizes, int n_in,
                              void* d_out, int out_size, void* d_ws, size_t ws_size,
                              hipStream_t stream) {
    const v4f* x   = (const v4f*)d_in[0];
    const int* tp  = (const int*)d_in[1];
    v4f*       out = (v4f*)d_out;

    // Launch #1 — the real work.
    RotaryPositionalEmbedding_68332929679843_kernel<<<dim3(NTHREADS / 256),
                                                      dim3(256), 0, stream>>>(x, tp, out);
    // Launch #2 — identical, serialized, bit-identical overwrite.
    // Purely diagnostic: total dur_us grows by exactly one true kernel time.
    RotaryPositionalEmbedding_68332929679843_kernel<<<dim3(NTHREADS / 256),
                                                      dim3(256), 0, stream>>>(x, tp, out);
}

// Round 8
// 404.111 us; speedup vs baseline: 1.1035x; 1.1035x over previous
//
#include <hip/hip_runtime.h>
#include <math.h>

// Fully-fused RoPE, single kernel — FINAL (restores Round-5 best after the
// Round-7 double-launch diagnostic).
//
// x: [B=4, H=16, S=4096, D=128] f32 (134 MB) -> out same shape. pos: [S] i32.
// R input unused (block-diag 2x2 rotations reconstructed analytically:
// cos/sin(pos[s] * theta^(-k/64)), theta = 10000).
//
// MEASURED (Round 7, launch-twice diagnostic): true kernel time = 40.7 us
// = 268.4 MB / 40.7 us = 6.59 TB/s — at the chip's demonstrated HBM ceiling
// (harness fills: 6.5-6.7 TB/s; m13 float4-copy ubench: 6.29 TB/s).
// The kernel is memory-roofline-bound; remaining dur_us (~364 us) is
// harness-fixed poison-fill/restore work outside kernel_launch's control.
//
// Structure: rotation (s,c4) is identical across all 64 bh slices (stride
// 2 MB). Each thread computes its rotation ONCE in registers (2 sincos,
// amortized over 16 slices) and streams 16 float4s with nontemporal
// loads/stores (A/B-tested vs cached in Rounds 5/6: nt is ~6 us better).
// No table, no LDS, no d_ws, single launch.
//
// Layout: thread g (0..524287): tab = g & 131071 = s*32 + c4,
// bh0 = (g>>17)*16. i4 = bh*131072 + tab. Consecutive lanes ->
// consecutive i4: perfectly coalesced per slice.
// Grid 2048 x 256 = 8 blocks/CU, full occupancy at ~48 VGPR.

typedef float v4f __attribute__((ext_vector_type(4)));

#define ROPE_S     4096
#define TAB_N4     (ROPE_S*32)      // 131072 unique (s,c4) rotations
#define NBH        64               // B*H
#define SLICES     16               // bh slices per thread
#define NTHREADS   (TAB_N4*(NBH/SLICES))  // 524288
// -log2(theta)/64 = -log2(10000)/64
#define NEG_L2T_64 (-0.20762050593046012f)

__global__ __launch_bounds__(256) void
RotaryPositionalEmbedding_68332929679843_kernel(const v4f* __restrict__ x,
                                                const int* __restrict__ pos,
                                                v4f* __restrict__ out) {
    const int g   = blockIdx.x * 256 + threadIdx.x;  // 0..524287
    const int tab = g & (TAB_N4 - 1);                // s*32 + c4
    const int bh0 = (g >> 17) * SLICES;              // 0 / 16 / 32 / 48
    const int s   = tab >> 5;
    const int c4  = tab & 31;

    const float p = (float)pos[s];
    const int k   = c4 * 2;
    const float invf0 = exp2f((float)k       * NEG_L2T_64); // theta^(-k/64)
    const float invf1 = exp2f((float)(k + 1) * NEG_L2T_64);
    float s0, c0, s1, c1;
    sincosf(p * invf0, &s0, &c0);
    sincosf(p * invf1, &s1, &c1);

    const size_t base = (size_t)bh0 * TAB_N4 + (size_t)tab;

#pragma unroll
    for (int j = 0; j < SLICES; j += 4) {
        v4f v0 = __builtin_nontemporal_load(&x[base + (size_t)(j + 0) * TAB_N4]);
        v4f v1 = __builtin_nontemporal_load(&x[base + (size_t)(j + 1) * TAB_N4]);
        v4f v2 = __builtin_nontemporal_load(&x[base + (size_t)(j + 2) * TAB_N4]);
        v4f v3 = __builtin_nontemporal_load(&x[base + (size_t)(j + 3) * TAB_N4]);

        v4f o0, o1, o2, o3;
        o0.x = c0 * v0.x - s0 * v0.y;  o0.y = s0 * v0.x + c0 * v0.y;
        o0.z = c1 * v0.z - s1 * v0.w;  o0.w = s1 * v0.z + c1 * v0.w;
        o1.x = c0 * v1.x - s0 * v1.y;  o1.y = s0 * v1.x + c0 * v1.y;
        o1.z = c1 * v1.z - s1 * v1.w;  o1.w = s1 * v1.z + c1 * v1.w;
        o2.x = c0 * v2.x - s0 * v2.y;  o2.y = s0 * v2.x + c0 * v2.y;
        o2.z = c1 * v2.z - s1 * v2.w;  o2.w = s1 * v2.z + c1 * v2.w;
        o3.x = c0 * v3.x - s0 * v3.y;  o3.y = s0 * v3.x + c0 * v3.y;
        o3.z = c1 * v3.z - s1 * v3.w;  o3.w = s1 * v3.z + c1 * v3.w;

        __builtin_nontemporal_store(o0, &out[base + (size_t)(j + 0) * TAB_N4]);
        __builtin_nontemporal_store(o1, &out[base + (size_t)(j + 1) * TAB_N4]);
        __builtin_nontemporal_store(o2, &out[base + (size_t)(j + 2) * TAB_N4]);
        __builtin_nontemporal_store(o3, &out[base + (size_t)(j + 3) * TAB_N4]);
    }
}

extern "C" void kernel_launch(void* const* d_in, const int* in_sizes, int n_in,
                              void* d_out, int out_size, void* d_ws, size_t ws_size,
                              hipStream_t stream) {
    const v4f* x   = (const v4f*)d_in[0];
    const int* tp  = (const int*)d_in[1];
    v4f*       out = (v4f*)d_out;

    RotaryPositionalEmbedding_68332929679843_kernel<<<dim3(NTHREADS / 256),
                                                      dim3(256), 0, stream>>>(x, tp, out);
}